// Round 6
// baseline (537.851 us; speedup 1.0000x reference)
//
#include <hip/hip_runtime.h>

// HoughCriterion: gaussian center-splat target + focal loss + scalar reduce.
// h0 [8,80,128,128], h1 [8,80,64,64], h2 [8,80,32,32] fp32;
// boxes [8,32,4] fp32 cxcywh normalized; labels [8,32] i32; image_sizes unused.
//
// Single fused kernel:
//   Pass B (bid<768, dispatched first): per-(level,box) window correction.
//   Pass A (bid in [768,4608)): fine-grained pure focal-neg streaming.
//   Last-finished block (device-scope counter + fences) runs the finalize.
// negterm() is the identical instruction sequence in both passes so the
// Pass-B correction cancels Pass-A contributions exactly.
//
// ws float slots (all written unconditionally before counter bump):
//   [0,3840)     nl Pass-A partial per block
//   [3840,4608)  np per (lv,box)  slot = 3840 + lv*256 + box
//   [4608,5376)  pl per (lv,box)
//   [5376,6144)  nl-correction per (lv,box)
//   [6144]       completion counter (memset to 0 each launch)

#define BATCH 8
#define NBOX 32
#define NCH 80
#define NPLANE 640
#define NB_B 768
#define GRID (NB_B + 3840)

__device__ __forceinline__ float sigclip(float h) {
    const float e = __expf(-h);
    const float p = __builtin_amdgcn_rcpf(1.0f + e);   // v_rcp_f32
    return fminf(fmaxf(p, 1e-4f), 1.0f - 1e-4f);
}
__device__ __forceinline__ float negterm(float h) {
    const float p = sigclip(h);
    return __logf(1.0f - p) * p * p;
}

__global__ __launch_bounds__(256) void hough_fused_kernel(
    const float* __restrict__ h0, const float* __restrict__ h1,
    const float* __restrict__ h2,
    const float* __restrict__ boxes, const int* __restrict__ labels,
    float* __restrict__ ws, unsigned int* __restrict__ cnt,
    float* __restrict__ out)
{
    const int bid = blockIdx.x;
    const int tid = threadIdx.x;

    __shared__ float red[12];        // per-wave reduction scratch
    __shared__ int   s_lab[NBOX];
    __shared__ int   s_xm[NBOX], s_ym[NBOX], s_rm[NBOX];
    __shared__ float s_i2[NBOX];
    __shared__ int   s_cand[NBOX];
    __shared__ int   s_kc;
    __shared__ int   s_last;
    const int w = tid >> 6, l = tid & 63;

    if (bid >= NB_B) {
        // ------------- Pass A: fine-grained focal-neg streaming -------------
        const int aid = bid - NB_B;
        const float* hp; int nf4;
        if (aid < 2560) {            // level0: plane=aid>>2, chunk=aid&3
            hp = h0 + ((size_t)aid << 12); nf4 = 1024;
        } else if (aid < 3200) {     // level1
            hp = h1 + ((size_t)(aid - 2560) << 12); nf4 = 1024;
        } else {                     // level2
            hp = h2 + ((size_t)(aid - 3200) << 10); nf4 = 256;
        }
        const float4* f4 = (const float4*)hp;
        float nl = 0.0f;
        for (int i = tid; i < nf4; i += 256) {
            const float4 q = f4[i];
            nl += negterm(q.x) + negterm(q.y) + negterm(q.z) + negterm(q.w);
        }
        for (int o = 32; o > 0; o >>= 1) nl += __shfl_down(nl, o, 64);
        if (l == 0) red[w] = nl;
        __syncthreads();
        if (tid == 0) ws[aid] = red[0] + red[1] + red[2] + red[3];
    } else {
        // ------------- Pass B: per-(level,box) window correction -------------
        const int lv = bid >> 8;          // 0,1,2
        const int box = bid & 255;
        const int b = box >> 5, n = box & 31;
        const int lw = 7 - lv;
        const int W = 1 << lw;
        const float fW = (float)W;

        if (tid < NBOX) {
            s_lab[tid] = labels[b * NBOX + tid];
            const float* bp = boxes + (size_t)(b * NBOX + tid) * 4;
            s_xm[tid] = (int)floorf(bp[0] * fW);
            s_ym[tid] = (int)floorf(bp[1] * fW);
            int r = (int)floorf((bp[2] * fW + bp[3] * fW) * 0.25f);
            r = max(1, r);
            s_rm[tid] = r;
            const float sig = (float)(2 * r + 1) / 6.0f;
            s_i2[tid] = 1.0f / (2.0f * sig * sig);
        }
        __syncthreads();
        const int c = s_lab[n];
        if (tid == 0) {
            int kc = 0;
            for (int m = 0; m < NBOX; ++m)
                if (s_lab[m] == c) s_cand[kc++] = m;   // ascending
            s_kc = kc;
        }
        __syncthreads();
        const int kc = s_kc;

        const int xn = s_xm[n], yn = s_ym[n], rn = s_rm[n];
        const int wn = 2 * rn + 1;
        const int tot = wn * wn;
        const float inv_wn = __builtin_amdgcn_rcpf((float)wn);
        const float* hb = ((lv == 0) ? h0 : (lv == 1) ? h1 : h2)
                          + ((size_t)(b * NCH + c) << (2 * lw));

        float np_ = 0.0f, pl_ = 0.0f, nld = 0.0f;
        for (int idx = tid; idx < tot; idx += 256) {
            int dy = (int)((float)idx * inv_wn);
            int rem = idx - dy * wn;
            if (rem < 0)        { dy -= 1; rem += wn; }
            else if (rem >= wn) { dy += 1; rem -= wn; }
            const int px = xn - rn + rem;
            const int py = yn - rn + dy;
            if (px < 0 || px >= W || py < 0 || py >= W) continue;

            bool owned = true;
            float t = 0.0f;
            for (int j = 0; j < kc; ++j) {
                const int m = s_cand[j];
                const int rm = s_rm[m];
                const int ddx = px - s_xm[m], ddy = py - s_ym[m];
                if (ddx < -rm || ddx > rm || ddy < -rm || ddy > rm) continue;
                if (m < n) { owned = false; break; }   // earlier box owns px
                t = fmaxf(t, __expf(-(float)(ddx * ddx + ddy * ddy) * s_i2[m]));
            }
            if (!owned) continue;

            const float h = hb[py * W + px];
            const float n0 = negterm(h);          // what Pass A already added
            if (t == 1.0f) {                      // exact only at a box center
                const float p = sigclip(h);
                const float omp = 1.0f - p;
                pl_ += __logf(p) * omp * omp;
                np_ += 1.0f;
                nld -= n0;                        // remove neg contribution
            } else {
                const float omt = 1.0f - t;
                const float nw4 = (omt * omt) * (omt * omt);
                nld += n0 * (nw4 - 1.0f);         // reweight correction
            }
        }

        for (int o = 32; o > 0; o >>= 1) {
            np_ += __shfl_down(np_, o, 64);
            pl_ += __shfl_down(pl_, o, 64);
            nld += __shfl_down(nld, o, 64);
        }
        if (l == 0) { red[w] = np_; red[4 + w] = pl_; red[8 + w] = nld; }
        __syncthreads();
        if (tid == 0) {
            const int slot = lv * 256 + box;
            ws[3840 + slot] = red[0] + red[1] + red[2] + red[3];
            ws[4608 + slot] = red[4] + red[5] + red[6] + red[7];
            ws[5376 + slot] = red[8] + red[9] + red[10] + red[11];
        }
    }

    // ---------------- completion + last-block finalize ----------------
    __threadfence();                       // release: partials visible first
    if (tid == 0) {
        const unsigned int old = atomicAdd(cnt, 1u);
        s_last = (old == (unsigned int)(GRID - 1)) ? 1 : 0;
    }
    __syncthreads();
    if (!s_last) return;

    __threadfence();                       // acquire side
    volatile const float* vws = ws;
    float s = 0.0f;
    for (int p = tid; p < NPLANE; p += 256) {
        const int b = p / NCH, c = p - b * NCH;
        float nl = vws[4 * p] + vws[4 * p + 1] + vws[4 * p + 2] + vws[4 * p + 3]
                 + vws[2560 + p] + vws[3200 + p];
        float np_ = 0.0f, pl_ = 0.0f;
        for (int m = 0; m < NBOX; ++m) {
            if (labels[b * NBOX + m] == c) {
                const int box = b * NBOX + m;
                #pragma unroll
                for (int lv = 0; lv < 3; ++lv) {
                    const int slot = lv * 256 + box;
                    np_ += vws[3840 + slot];
                    pl_ += vws[4608 + slot];
                    nl  += vws[5376 + slot];
                }
            }
        }
        const float loss = (np_ == 0.0f) ? (-nl) : (-(pl_ + nl) / np_);
        s += fminf(loss, 10.0f);
    }
    for (int o = 32; o > 0; o >>= 1) s += __shfl_down(s, o, 64);
    __syncthreads();                       // red[] reuse
    if (l == 0) red[w] = s;
    __syncthreads();
    if (tid == 0) {
        const float mean = (red[0] + red[1] + red[2] + red[3]) * (1.0f / (float)NPLANE);
        const float lm = log1pf(mean);
        out[0] = lm / (1.0f + lm);
    }
}

extern "C" void kernel_launch(void* const* d_in, const int* in_sizes, int n_in,
                              void* d_out, int out_size, void* d_ws, size_t ws_size,
                              hipStream_t stream) {
    const float* h0 = (const float*)d_in[0];
    const float* h1 = (const float*)d_in[1];
    const float* h2 = (const float*)d_in[2];
    const float* boxes = (const float*)d_in[3];
    const int* labels = (const int*)d_in[4];
    // d_in[5] image_sizes: unused (cancels in reference math)

    float* ws = (float*)d_ws;                        // 6144 floats + counter
    unsigned int* cnt = (unsigned int*)(ws + 6144);

    hipMemsetAsync(cnt, 0, sizeof(unsigned int), stream);   // graph memset node
    hough_fused_kernel<<<GRID, 256, 0, stream>>>(h0, h1, h2, boxes, labels,
                                                 ws, cnt, (float*)d_out);
}

// Round 7
// 104.699 us; speedup vs baseline: 5.1371x; 5.1371x over previous
//
#include <hip/hip_runtime.h>

// HoughCriterion: gaussian center-splat target + focal loss + scalar reduce.
// h0 [8,80,128,128], h1 [8,80,64,64], h2 [8,80,32,32] fp32;
// boxes [8,32,4] fp32 cxcywh normalized; labels [8,32] i32; image_sizes unused.
//
// R2-proven grid shape: 3840 blocks (level0: 4 chunks/plane; level1/2:
// 1 block/plane), two kernels. Per block:
//   1) ballot-compacted candidate list (boxes of this (b,c), original order)
//   2) pure focal-neg streaming over the chunk (NO box logic in hot loop)
//   3) sparse correction over window∩chunk pixels only (~200 px, L1-hot)
// negterm() identical in stream and correction -> exact cancellation.
// NOTE R6: no __threadfence / single-kernel finalize — agent-scope fences
// per block = per-XCD L2 writeback storm (500 µs). Kernel boundary is free.
//
// ws float slots (all written unconditionally; no init needed):
//   np[0..3840), pl[3840..7680), nl[7680..11520)  indexed by bid
//   (level0: bid=plane*4+chunk; level1: 2560+plane; level2: 3200+plane)

#define BATCH 8
#define NBOX 32
#define NCH 80
#define NPLANE 640
#define NBLK 3840

__device__ __forceinline__ float sigclip(float h) {
    const float e = __expf(-h);
    const float p = __builtin_amdgcn_rcpf(1.0f + e);   // v_rcp_f32
    return fminf(fmaxf(p, 1e-4f), 1.0f - 1e-4f);
}
__device__ __forceinline__ float negterm(float h) {
    const float p = sigclip(h);
    return __logf(1.0f - p) * p * p;
}

__global__ __launch_bounds__(256) void splat_focal_kernel(
    const float* __restrict__ h0, const float* __restrict__ h1,
    const float* __restrict__ h2,
    const float* __restrict__ boxes, const int* __restrict__ labels,
    float* __restrict__ ws)
{
    const int bid = blockIdx.x;
    const int tid = threadIdx.x;

    int plane, log2W, row0, nrows;
    const float* heat;
    if (bid < 2560) {                    // level0: 128x128, 4 chunks of 32 rows
        plane = bid >> 2;
        const int chunk = bid & 3;
        log2W = 7; heat = h0 + ((size_t)plane << 14);
        row0 = chunk << 5; nrows = 32;
    } else if (bid < 3200) {             // level1: 64x64
        plane = bid - 2560;
        log2W = 6; heat = h1 + ((size_t)plane << 12);
        row0 = 0; nrows = 64;
    } else {                             // level2: 32x32
        plane = bid - 3200;
        log2W = 5; heat = h2 + ((size_t)plane << 10);
        row0 = 0; nrows = 32;
    }
    const int W = 1 << log2W;
    const int b = plane / NCH;
    const int c = plane - b * NCH;

    // --- candidate collection: order-preserving ballot compaction (wave 0)
    __shared__ int   s_k;
    __shared__ int   s_x[NBOX], s_y[NBOX], s_r[NBOX];
    __shared__ float s_i2[NBOX];
    if (tid < 64) {
        const int m = tid;
        const bool match = (m < NBOX) && (labels[b * NBOX + m] == c);
        const unsigned long long mask = __ballot(match);
        if (match) {
            const int pos = __popcll(mask & ((1ull << m) - 1ull));
            const float fW = (float)W;
            const float* bp = boxes + (size_t)(b * NBOX + m) * 4;
            s_x[pos] = (int)floorf(bp[0] * fW);
            s_y[pos] = (int)floorf(bp[1] * fW);
            int r = (int)floorf((bp[2] * fW + bp[3] * fW) * 0.25f);
            r = max(1, r);
            s_r[pos] = r;
            const float sig = (float)(2 * r + 1) / 6.0f;
            s_i2[pos] = 1.0f / (2.0f * sig * sig);
        }
        if (m == 0) s_k = __popcll(mask);
    }
    __syncthreads();
    const int k = s_k;

    // --- pure focal-neg streaming (no box logic)
    float np_ = 0.0f, pl_ = 0.0f, nl_ = 0.0f;
    const int nf4 = (nrows << log2W) >> 2;
    const float4* f4 = (const float4*)(heat + (row0 << log2W));
    for (int i = tid; i < nf4; i += 256) {
        const float4 q = f4[i];
        nl_ += negterm(q.x) + negterm(q.y) + negterm(q.z) + negterm(q.w);
    }

    // --- sparse correction over window ∩ chunk (L1-hot re-reads)
    if (k > 0) {
        const int row1 = row0 + nrows;
        for (int j = 0; j < k; ++j) {
            const int xj = s_x[j], yj = s_y[j], rj = s_r[j];
            int ylo = max(max(yj - rj, row0), 0);
            int yhi = min(min(yj + rj, row1 - 1), W - 1);
            int xlo = max(xj - rj, 0);
            int xhi = min(xj + rj, W - 1);
            const int ny = yhi - ylo + 1, nx = xhi - xlo + 1;
            if (ny <= 0 || nx <= 0) continue;
            const int tot = nx * ny;
            for (int idx = tid; idx < tot; idx += 256) {
                int py = idx / nx;
                const int px = xlo + (idx - py * nx);
                py += ylo;
                // ownership: first candidate (original order) covering px wins
                bool owned = true;
                for (int jj = 0; jj < j; ++jj) {
                    const int ax = px - s_x[jj], ay = py - s_y[jj];
                    if (ax >= -s_r[jj] && ax <= s_r[jj] &&
                        ay >= -s_r[jj] && ay <= s_r[jj]) { owned = false; break; }
                }
                if (!owned) continue;
                float t = 0.0f;
                for (int jj = 0; jj < k; ++jj) {
                    const int ax = px - s_x[jj], ay = py - s_y[jj];
                    const int rr = s_r[jj];
                    if (ax < -rr || ax > rr || ay < -rr || ay > rr) continue;
                    t = fmaxf(t, __expf(-(float)(ax * ax + ay * ay) * s_i2[jj]));
                }
                const float h = heat[(py << log2W) + px];
                const float n0 = negterm(h);      // what the stream added
                if (t == 1.0f) {                  // exact only at box center
                    const float p = sigclip(h);
                    const float omp = 1.0f - p;
                    pl_ += __logf(p) * omp * omp;
                    np_ += 1.0f;
                    nl_ -= n0;                    // remove neg contribution
                } else {
                    const float omt = 1.0f - t;
                    const float nw4 = (omt * omt) * (omt * omt);
                    nl_ += n0 * (nw4 - 1.0f);     // reweight correction
                }
            }
        }
    }

    // --- block reduce: wave64 shuffle then cross-wave via LDS
    for (int o = 32; o > 0; o >>= 1) {
        np_ += __shfl_down(np_, o, 64);
        pl_ += __shfl_down(pl_, o, 64);
        nl_ += __shfl_down(nl_, o, 64);
    }
    __shared__ float s_np[4], s_pl[4], s_nl[4];
    const int w = tid >> 6, l = tid & 63;
    if (l == 0) { s_np[w] = np_; s_pl[w] = pl_; s_nl[w] = nl_; }
    __syncthreads();
    if (tid == 0) {
        ws[bid]            = s_np[0] + s_np[1] + s_np[2] + s_np[3];
        ws[NBLK + bid]     = s_pl[0] + s_pl[1] + s_pl[2] + s_pl[3];
        ws[2 * NBLK + bid] = s_nl[0] + s_nl[1] + s_nl[2] + s_nl[3];
    }
}

__global__ __launch_bounds__(256) void finalize_kernel(
    const float* __restrict__ ws, float* __restrict__ out)
{
    const int tid = threadIdx.x;
    const float* np = ws;
    const float* pl = ws + NBLK;
    const float* nl = ws + 2 * NBLK;

    float s = 0.0f;
    for (int p = tid; p < NPLANE; p += 256) {
        const float4 n4 = ((const float4*)np)[p];   // level0 chunks 4p..4p+3
        const float4 p4 = ((const float4*)pl)[p];
        const float4 l4 = ((const float4*)nl)[p];
        const float a  = n4.x + n4.y + n4.z + n4.w + np[2560 + p] + np[3200 + p];
        const float ps = p4.x + p4.y + p4.z + p4.w + pl[2560 + p] + pl[3200 + p];
        const float ns = l4.x + l4.y + l4.z + l4.w + nl[2560 + p] + nl[3200 + p];
        const float loss = (a == 0.0f) ? (-ns) : (-(ps + ns) / a);
        s += fminf(loss, 10.0f);
    }
    for (int o = 32; o > 0; o >>= 1) s += __shfl_down(s, o, 64);
    __shared__ float sw[4];
    const int w = tid >> 6, l = tid & 63;
    if (l == 0) sw[w] = s;
    __syncthreads();
    if (tid == 0) {
        const float mean = (sw[0] + sw[1] + sw[2] + sw[3]) * (1.0f / (float)NPLANE);
        const float lm = log1pf(mean);
        out[0] = lm / (1.0f + lm);
    }
}

extern "C" void kernel_launch(void* const* d_in, const int* in_sizes, int n_in,
                              void* d_out, int out_size, void* d_ws, size_t ws_size,
                              hipStream_t stream) {
    const float* h0 = (const float*)d_in[0];
    const float* h1 = (const float*)d_in[1];
    const float* h2 = (const float*)d_in[2];
    const float* boxes = (const float*)d_in[3];
    const int* labels = (const int*)d_in[4];
    // d_in[5] image_sizes: unused (cancels in reference math)

    float* ws = (float*)d_ws;   // 3*NBLK floats, fully overwritten every call

    splat_focal_kernel<<<NBLK, 256, 0, stream>>>(h0, h1, h2, boxes, labels, ws);
    finalize_kernel<<<1, 256, 0, stream>>>(ws, (float*)d_out);
}